// Round 2
// baseline (3263.000 us; speedup 1.0000x reference)
//
#include <hip/hip_runtime.h>
#include <hip/hip_bf16.h>

// Problem constants: x [B=64, C=256, H=32, W=32] f32, embedding [K=4096, D=256] f32
// N = B*H*W = 65536 rows; row n=(b,h,w) vector over c: x[b][c][h][w] (stride 1024 floats in c)
// Outputs concatenated in d_out: out[B,C,H,W] (16777216 f32), loss (1), perplexity (1)

#define N_TOT 65536
#define K_CODES 4096
#define D_DIM 256

// ---------------- Kernel A: Se[k] = sum_d e[k][d]^2 ----------------
__global__ __launch_bounds__(256) void vq_se(const float* __restrict__ emb,
                                             float* __restrict__ Se) {
    int k = blockIdx.x * 256 + threadIdx.x;
    const float* e = emb + ((size_t)k << 8);
    float s = 0.f;
#pragma unroll
    for (int d = 0; d < 256; d += 4) {
        float4 v = *(const float4*)(e + d);
        s += v.x * v.x + v.y * v.y + v.z * v.z + v.w * v.w;
    }
    Se[k] = s;
}

// ---------------- Kernel B: argmin_k ( Se[k] - 2 * x_n . e_k ) ----------------
// Block: 256 threads, 32 rows. Loop codes in chunks of 256, dims in chunks of 32.
__global__ __launch_bounds__(256) void vq_argmin(const float* __restrict__ x,
                                                 const float* __restrict__ emb,
                                                 const float* __restrict__ Se,
                                                 int* __restrict__ idx_out,
                                                 unsigned int* __restrict__ counts) {
    __shared__ float xs[256][32];    // [d][n] 32 KB
    __shared__ float es[32][256];    // [dd][k] 32 KB
    __shared__ float red_s[32][33];
    __shared__ int   red_i[32][33];

    const int t = threadIdx.x;
    const int n0 = blockIdx.x * 32;
    const int b = n0 >> 10;
    const int hw0 = n0 & 1023;

    // stage x tile: xs[d][nj] = x[b][d][hw0+nj]  (coalesced: 32 consecutive floats per d)
    {
        const int nj = t & 31;
        const int d0 = t >> 5;  // 0..7
        const float* xb = x + ((size_t)b << 18) + hw0 + nj;
#pragma unroll
        for (int d = d0; d < 256; d += 8) xs[d][nj] = xb[(size_t)d << 10];
    }

    const int ti = t & 7;   // rows ti*4 .. ti*4+3
    const int tj = t >> 3;  // codes tj*8 .. tj*8+7 within chunk

    float best[4] = {1e30f, 1e30f, 1e30f, 1e30f};
    int bidx[4] = {0, 0, 0, 0};

    for (int kc = 0; kc < K_CODES; kc += 256) {
        float acc[4][8];
#pragma unroll
        for (int i = 0; i < 4; ++i)
#pragma unroll
            for (int j = 0; j < 8; ++j) acc[i][j] = 0.f;

        for (int ds = 0; ds < 256; ds += 32) {
            __syncthreads();
            // stage es[dd][k] for codes kc..kc+255, dims ds..ds+31
            {
                const int krow = t >> 2;       // 0..63
                const int dsub = (t & 3) * 4;  // 0,4,8,12
#pragma unroll
                for (int p = 0; p < 4; ++p) {
                    const int kk = krow + p * 64;
                    const float* ep = emb + (((size_t)(kc + kk)) << 8) + ds + dsub;
                    float4 v0 = *(const float4*)ep;
                    float4 v1 = *(const float4*)(ep + 16);
                    es[dsub + 0][kk] = v0.x;
                    es[dsub + 1][kk] = v0.y;
                    es[dsub + 2][kk] = v0.z;
                    es[dsub + 3][kk] = v0.w;
                    es[dsub + 16][kk] = v1.x;
                    es[dsub + 17][kk] = v1.y;
                    es[dsub + 18][kk] = v1.z;
                    es[dsub + 19][kk] = v1.w;
                }
            }
            __syncthreads();
#pragma unroll 8
            for (int dd = 0; dd < 32; ++dd) {
                const int d = ds + dd;
                float4 xv = *(const float4*)&xs[d][ti * 4];
                float4 e0 = *(const float4*)&es[dd][tj * 8];
                float4 e1 = *(const float4*)&es[dd][tj * 8 + 4];
                acc[0][0] = fmaf(xv.x, e0.x, acc[0][0]);
                acc[0][1] = fmaf(xv.x, e0.y, acc[0][1]);
                acc[0][2] = fmaf(xv.x, e0.z, acc[0][2]);
                acc[0][3] = fmaf(xv.x, e0.w, acc[0][3]);
                acc[0][4] = fmaf(xv.x, e1.x, acc[0][4]);
                acc[0][5] = fmaf(xv.x, e1.y, acc[0][5]);
                acc[0][6] = fmaf(xv.x, e1.z, acc[0][6]);
                acc[0][7] = fmaf(xv.x, e1.w, acc[0][7]);
                acc[1][0] = fmaf(xv.y, e0.x, acc[1][0]);
                acc[1][1] = fmaf(xv.y, e0.y, acc[1][1]);
                acc[1][2] = fmaf(xv.y, e0.z, acc[1][2]);
                acc[1][3] = fmaf(xv.y, e0.w, acc[1][3]);
                acc[1][4] = fmaf(xv.y, e1.x, acc[1][4]);
                acc[1][5] = fmaf(xv.y, e1.y, acc[1][5]);
                acc[1][6] = fmaf(xv.y, e1.z, acc[1][6]);
                acc[1][7] = fmaf(xv.y, e1.w, acc[1][7]);
                acc[2][0] = fmaf(xv.z, e0.x, acc[2][0]);
                acc[2][1] = fmaf(xv.z, e0.y, acc[2][1]);
                acc[2][2] = fmaf(xv.z, e0.z, acc[2][2]);
                acc[2][3] = fmaf(xv.z, e0.w, acc[2][3]);
                acc[2][4] = fmaf(xv.z, e1.x, acc[2][4]);
                acc[2][5] = fmaf(xv.z, e1.y, acc[2][5]);
                acc[2][6] = fmaf(xv.z, e1.z, acc[2][6]);
                acc[2][7] = fmaf(xv.z, e1.w, acc[2][7]);
                acc[3][0] = fmaf(xv.w, e0.x, acc[3][0]);
                acc[3][1] = fmaf(xv.w, e0.y, acc[3][1]);
                acc[3][2] = fmaf(xv.w, e0.z, acc[3][2]);
                acc[3][3] = fmaf(xv.w, e0.w, acc[3][3]);
                acc[3][4] = fmaf(xv.w, e1.x, acc[3][4]);
                acc[3][5] = fmaf(xv.w, e1.y, acc[3][5]);
                acc[3][6] = fmaf(xv.w, e1.z, acc[3][6]);
                acc[3][7] = fmaf(xv.w, e1.w, acc[3][7]);
            }
        }
        // fold chunk scores into running argmin (k ascending, strict < => first index)
        const int kbase = kc + tj * 8;
#pragma unroll
        for (int j = 0; j < 8; ++j) {
            const float se = Se[kbase + j];
#pragma unroll
            for (int i = 0; i < 4; ++i) {
                const float s = fmaf(-2.0f, acc[i][j], se);
                if (s < best[i]) { best[i] = s; bidx[i] = kbase + j; }
            }
        }
    }

    // cross-thread reduce (over tj groups) per row
#pragma unroll
    for (int i = 0; i < 4; ++i) {
        red_s[ti * 4 + i][tj] = best[i];
        red_i[ti * 4 + i][tj] = bidx[i];
    }
    __syncthreads();
    if (t < 32) {
        float bs = red_s[t][0];
        int bi = red_i[t][0];
        for (int j = 1; j < 32; ++j) {
            const float s2 = red_s[t][j];
            const int i2 = red_i[t][j];
            if (s2 < bs || (s2 == bs && i2 < bi)) { bs = s2; bi = i2; }
        }
        idx_out[n0 + t] = bi;
        atomicAdd(&counts[bi], 1u);
    }
}

// ---------------- Kernel C: fused quantized output + MSE accumulation ----------------
// grid = B*C blocks (16384); block 256 threads, each thread 4 hw via float4.
__global__ __launch_bounds__(256) void vq_out(const float* __restrict__ x,
                                              const float* __restrict__ emb,
                                              const int* __restrict__ idx,
                                              float* __restrict__ out,
                                              double* __restrict__ loss_acc) {
    __shared__ double sd[256];
    const int t = threadIdx.x;
    const int bc = blockIdx.x;  // b*256 + c
    const int b = bc >> 8, c = bc & 255;
    const size_t base = (size_t)bc << 10;
    const int hw = t * 4;
    float4 xv = *(const float4*)(x + base + hw);
    int4 iv = *(const int4*)(idx + (b << 10) + hw);
    const float q0 = emb[((size_t)iv.x << 8) + c];
    const float q1 = emb[((size_t)iv.y << 8) + c];
    const float q2 = emb[((size_t)iv.z << 8) + c];
    const float q3 = emb[((size_t)iv.w << 8) + c];
    const float d0 = q0 - xv.x, d1 = q1 - xv.y, d2 = q2 - xv.z, d3 = q3 - xv.w;
    float4 o;
    o.x = xv.x + d0;  // straight-through: fl(xt + fl(q - xt))
    o.y = xv.y + d1;
    o.z = xv.z + d2;
    o.w = xv.w + d3;
    *(float4*)(out + base + hw) = o;
    sd[t] = (double)d0 * d0 + (double)d1 * d1 + (double)d2 * d2 + (double)d3 * d3;
    __syncthreads();
    for (int off = 128; off > 0; off >>= 1) {
        if (t < off) sd[t] += sd[t + off];
        __syncthreads();
    }
    if (t == 0) atomicAdd(loss_acc, sd[0]);
}

// ---------------- Kernel D: finalize loss + perplexity ----------------
__global__ __launch_bounds__(256) void vq_final(const unsigned int* __restrict__ counts,
                                                const double* __restrict__ loss_acc,
                                                float* __restrict__ out_scalars) {
    __shared__ double sd[256];
    const int t = threadIdx.x;
    double s = 0.0;
    for (int j = t; j < K_CODES; j += 256) {
        const double p = (double)counts[j] * (1.0 / 65536.0);
        s += p * log(p + 1e-10);
    }
    sd[t] = s;
    __syncthreads();
    for (int off = 128; off > 0; off >>= 1) {
        if (t < off) sd[t] += sd[t + off];
        __syncthreads();
    }
    if (t == 0) {
        const double mse = loss_acc[0] / 16777216.0;  // mean over B*H*W*D
        out_scalars[0] = (float)(1.25 * mse);         // q_latent + 0.25*e_latent
        out_scalars[1] = (float)exp(-sd[0]);          // perplexity
    }
}

extern "C" void kernel_launch(void* const* d_in, const int* in_sizes, int n_in,
                              void* d_out, int out_size, void* d_ws, size_t ws_size,
                              hipStream_t stream) {
    const float* x = (const float*)d_in[0];    // 16777216 f32
    const float* emb = (const float*)d_in[1];  // 1048576 f32
    float* out = (float*)d_out;                // 16777216 f32 quantized + 2 scalars

    char* ws = (char*)d_ws;
    double* loss_acc = (double*)ws;                       // 8 B @ 0
    unsigned int* counts = (unsigned int*)(ws + 256);     // 16 KB @ 256
    float* Se = (float*)(ws + 16640);                     // 16 KB
    int* idx = (int*)(ws + 33088);                        // 256 KB (16B aligned)

    hipMemsetAsync(ws, 0, 16640, stream);  // zero loss_acc + counts
    vq_se<<<K_CODES / 256, 256, 0, stream>>>(emb, Se);
    vq_argmin<<<N_TOT / 32, 256, 0, stream>>>(x, emb, Se, idx, counts);
    vq_out<<<64 * 256, 256, 0, stream>>>(x, emb, idx, out, loss_acc);
    // scalars live at the very end of the concatenated output
    vq_final<<<1, 256, 0, stream>>>(counts, loss_acc, out + (out_size - 2));
}

// Round 3
// 600.338 us; speedup vs baseline: 5.4353x; 5.4353x over previous
//
#include <hip/hip_runtime.h>
#include <hip/hip_bf16.h>

// x [B=64, C=256, H=32, W=32] f32; embedding [K=4096, D=256] f32
// N = 65536 rows. Outputs: out[B,C,H,W] f32 (16777216), loss, perplexity.

#define K_CODES 4096

typedef __attribute__((ext_vector_type(8))) short bf16x8;
typedef __attribute__((ext_vector_type(4))) float f32x4;
typedef __attribute__((ext_vector_type(8))) unsigned short u16x8;

__device__ __forceinline__ void gload_lds16(const void* g, void* l) {
    __builtin_amdgcn_global_load_lds((const __attribute__((address_space(1))) unsigned int*)g,
                                     (__attribute__((address_space(3))) unsigned int*)l,
                                     16, 0, 0);
}

__device__ __forceinline__ unsigned short f2bf(float v) {
    __hip_bfloat16 h = __float2bfloat16(v);
    return *(unsigned short*)&h;
}

// ---------------- emb f32 -> bf16, plus exact fp32 Se[k] ----------------
__global__ __launch_bounds__(64) void vq_prep_emb(const float* __restrict__ emb,
                                                  unsigned short* __restrict__ embB,
                                                  float* __restrict__ Se) {
    const int k = blockIdx.x, t = threadIdx.x;
    const float* e = emb + ((size_t)k << 8) + t * 4;
    float4 v = *(const float4*)e;
    ushort4 o;
    o.x = f2bf(v.x); o.y = f2bf(v.y); o.z = f2bf(v.z); o.w = f2bf(v.w);
    *(ushort4*)(embB + ((size_t)k << 8) + t * 4) = o;
    float s = v.x * v.x + v.y * v.y + v.z * v.z + v.w * v.w;
#pragma unroll
    for (int m = 1; m < 64; m <<= 1) s += __shfl_xor(s, m, 64);
    if (t == 0) Se[k] = s;
}

// ---------------- x [b][c][hw] f32 -> xT [b*1024+hw][c] bf16 ----------------
__global__ __launch_bounds__(256) void vq_transpose(const float* __restrict__ x,
                                                    unsigned short* __restrict__ xT) {
    __shared__ float tile[64][65];
    const int bid = blockIdx.x;
    const int ht = bid & 15, ct = (bid >> 4) & 3, b = bid >> 6;
    const int hw0 = ht * 64, c0 = ct * 64;
    const int t = threadIdx.x;
    {
        const int hwl = t & 63, cl = t >> 6;  // cl 0..3
        const float* xp = x + ((size_t)b << 18) + ((size_t)c0 << 10) + hw0 + hwl;
#pragma unroll
        for (int i = 0; i < 16; ++i)
            tile[cl + i * 4][hwl] = xp[(size_t)(cl + i * 4) << 10];
    }
    __syncthreads();
    {
        const int hwl = t >> 2, cs = (t & 3) * 16;
        unsigned short* op = xT + ((size_t)(b * 1024 + hw0 + hwl) << 8) + c0 + cs;
        u16x8 p0, p1;
#pragma unroll
        for (int j = 0; j < 8; ++j) p0[j] = f2bf(tile[cs + j][hwl]);
#pragma unroll
        for (int j = 0; j < 8; ++j) p1[j] = f2bf(tile[cs + 8 + j][hwl]);
        *(u16x8*)op = p0;
        *(u16x8*)(op + 8) = p1;
    }
}

// ---------------- MFMA argmin ----------------
// 512 blocks x 128 threads (2 waves). Wave owns 64 rows (4 frags of 16).
// Code chunks of 128 (8 frags of 16), d chunks of 64 (2 MFMA k-steps of 32).
// LDS: xs[128][256] bf16 swizzled (64KB) + es[128][64] bf16 swizzled (16KB).
__global__ __launch_bounds__(128, 1) void vq_argmin_mfma(
    const unsigned short* __restrict__ xT,
    const unsigned short* __restrict__ embB,
    const float* __restrict__ Se,
    int* __restrict__ idx_out,
    unsigned int* __restrict__ counts) {
    extern __shared__ char smem[];
    char* xsb = smem;            // 65536 B
    char* esb = smem + 65536;    // 16384 B

    const int t = threadIdx.x;
    const int w = t >> 6;
    const int l = t & 63;
    const int g = l >> 4;   // k-group 0..3
    const int r = l & 15;   // row-within-frag (A) / code-within-frag (B,C)
    const int n0 = blockIdx.x * 128;
    const int wrow = w * 64;
    const int swz = (r & 7) << 4;

    // stage xs once: LDS[row][col] = xT[n0+row][ (col ^ ((row&7)<<4)) /2 ]
#pragma unroll
    for (int i = 0; i < 32; ++i) {
        const int obase = (w * 32 + i) * 1024;       // uniform per wave-inst
        const int o = obase + l * 16;                // per-lane linear dest
        const int row = o >> 9;
        const int scol = (o & 511) ^ ((row & 7) << 4);
        gload_lds16(xT + ((size_t)(n0 + row) << 8) + (scol >> 1), xsb + obase);
    }

    float best[16];
    int bidx[16];
#pragma unroll
    for (int i = 0; i < 16; ++i) { best[i] = 1e30f; bidx[i] = 0; }

    for (int cb = 0; cb < K_CODES; cb += 128) {
        f32x4 acc[4][8];
#pragma unroll
        for (int rf = 0; rf < 4; ++rf)
#pragma unroll
            for (int f = 0; f < 8; ++f) acc[rf][f] = (f32x4){0.f, 0.f, 0.f, 0.f};

        for (int dk = 0; dk < 256; dk += 64) {
            __syncthreads();  // prior readers of es are done
            // stage es chunk: LDS[row][col] = embB[cb+row][dk + (col^swz(row))/2]
#pragma unroll
            for (int i = 0; i < 8; ++i) {
                const int obase = (w * 8 + i) * 1024;
                const int o = obase + l * 16;
                const int row = o >> 7;
                const int scol = (o & 127) ^ ((row & 7) << 4);
                gload_lds16(embB + ((size_t)(cb + row) << 8) + dk + (scol >> 1),
                            esb + obase);
            }
            __syncthreads();  // es staged (vmcnt drained by barrier)

#pragma unroll
            for (int ks = 0; ks < 2; ++ks) {
                const int colA = (dk + ks * 32 + g * 8) * 2;  // byte col in 512B row
                const int colB = (ks * 32 + g * 8) * 2;       // byte col in 128B row
                const int cA = colA ^ swz;
                const int cB = colB ^ swz;
                bf16x8 af[4];
#pragma unroll
                for (int rf = 0; rf < 4; ++rf) {
                    const int row = wrow + rf * 16 + r;
                    af[rf] = *(const bf16x8*)(xsb + row * 512 + cA);
                }
#pragma unroll
                for (int f = 0; f < 8; ++f) {
                    const int row = f * 16 + r;
                    bf16x8 bv = *(const bf16x8*)(esb + row * 128 + cB);
#pragma unroll
                    for (int rf = 0; rf < 4; ++rf)
                        acc[rf][f] = __builtin_amdgcn_mfma_f32_16x16x32_bf16(
                            af[rf], bv, acc[rf][f], 0, 0, 0);
                }
            }
        }

        // fold chunk into running argmin. lane covers code c = cb + f*16 + r,
        // rows wrow + rf*16 + g*4 + reg.
#pragma unroll
        for (int f = 0; f < 8; ++f) {
            const float se = Se[cb + f * 16 + r];
            const int c = cb + f * 16 + r;
#pragma unroll
            for (int rf = 0; rf < 4; ++rf)
#pragma unroll
                for (int reg = 0; reg < 4; ++reg) {
                    const float s = fmaf(-2.0f, acc[rf][f][reg], se);
                    const int sl = rf * 4 + reg;
                    if (s < best[sl]) { best[sl] = s; bidx[sl] = c; }
                }
        }
    }

    // reduce over the 16 code-lanes (same g), then write
#pragma unroll
    for (int sl = 0; sl < 16; ++sl) {
        float bs = best[sl];
        int bi = bidx[sl];
#pragma unroll
        for (int m = 1; m < 16; m <<= 1) {
            const float os = __shfl_xor(bs, m, 64);
            const int oi = __shfl_xor(bi, m, 64);
            if (os < bs || (os == bs && oi < bi)) { bs = os; bi = oi; }
        }
        if (r == 0) {
            const int rf = sl >> 2, reg = sl & 3;
            const int row = n0 + wrow + rf * 16 + g * 4 + reg;
            idx_out[row] = bi;
            atomicAdd(&counts[bi], 1u);
        }
    }
}

// ---------------- fused quantized output + MSE accumulation ----------------
__global__ __launch_bounds__(256) void vq_out(const float* __restrict__ x,
                                              const float* __restrict__ emb,
                                              const int* __restrict__ idx,
                                              float* __restrict__ out,
                                              double* __restrict__ loss_acc) {
    __shared__ double sd[256];
    const int t = threadIdx.x;
    const int bc = blockIdx.x;  // b*256 + c
    const int b = bc >> 8, c = bc & 255;
    const size_t base = (size_t)bc << 10;
    const int hw = t * 4;
    float4 xv = *(const float4*)(x + base + hw);
    int4 iv = *(const int4*)(idx + (b << 10) + hw);
    const float q0 = emb[((size_t)iv.x << 8) + c];
    const float q1 = emb[((size_t)iv.y << 8) + c];
    const float q2 = emb[((size_t)iv.z << 8) + c];
    const float q3 = emb[((size_t)iv.w << 8) + c];
    const float d0 = q0 - xv.x, d1 = q1 - xv.y, d2 = q2 - xv.z, d3 = q3 - xv.w;
    float4 o;
    o.x = xv.x + d0;
    o.y = xv.y + d1;
    o.z = xv.z + d2;
    o.w = xv.w + d3;
    *(float4*)(out + base + hw) = o;
    sd[t] = (double)d0 * d0 + (double)d1 * d1 + (double)d2 * d2 + (double)d3 * d3;
    __syncthreads();
    for (int off = 128; off > 0; off >>= 1) {
        if (t < off) sd[t] += sd[t + off];
        __syncthreads();
    }
    if (t == 0) atomicAdd(loss_acc, sd[0]);
}

// ---------------- finalize loss + perplexity ----------------
__global__ __launch_bounds__(256) void vq_final(const unsigned int* __restrict__ counts,
                                                const double* __restrict__ loss_acc,
                                                float* __restrict__ out_scalars) {
    __shared__ double sd[256];
    const int t = threadIdx.x;
    double s = 0.0;
    for (int j = t; j < K_CODES; j += 256) {
        const double p = (double)counts[j] * (1.0 / 65536.0);
        s += p * log(p + 1e-10);
    }
    sd[t] = s;
    __syncthreads();
    for (int off = 128; off > 0; off >>= 1) {
        if (t < off) sd[t] += sd[t + off];
        __syncthreads();
    }
    if (t == 0) {
        const double mse = loss_acc[0] / 16777216.0;
        out_scalars[0] = (float)(1.25 * mse);
        out_scalars[1] = (float)exp(-sd[0]);
    }
}

extern "C" void kernel_launch(void* const* d_in, const int* in_sizes, int n_in,
                              void* d_out, int out_size, void* d_ws, size_t ws_size,
                              hipStream_t stream) {
    const float* x = (const float*)d_in[0];    // 16777216 f32
    const float* emb = (const float*)d_in[1];  // 1048576 f32
    float* out = (float*)d_out;

    char* ws = (char*)d_ws;
    double* loss_acc = (double*)ws;                         // @0
    unsigned int* counts = (unsigned int*)(ws + 1024);      // 16 KB
    float* Se = (float*)(ws + 20480);                       // 16 KB
    int* idx = (int*)(ws + 36864);                          // 256 KB
    unsigned short* embB = (unsigned short*)(ws + 299008);  // 2 MB bf16
    unsigned short* xT = (unsigned short*)(ws + 2396160);   // 32 MB bf16

    hipMemsetAsync(ws, 0, 20480, stream);  // loss_acc + counts
    vq_prep_emb<<<K_CODES, 64, 0, stream>>>(emb, embB, Se);
    vq_transpose<<<4096, 256, 0, stream>>>(x, xT);
    vq_argmin_mfma<<<512, 128, 81920, stream>>>(xT, embB, Se, idx, counts);
    vq_out<<<64 * 256, 256, 0, stream>>>(x, emb, idx, out, loss_acc);
    vq_final<<<1, 256, 0, stream>>>(counts, loss_acc, out + (out_size - 2));
}